// Round 4
// baseline (580.903 us; speedup 1.0000x reference)
//
#include <hip/hip_runtime.h>

// TranslationRotationLoss: out = mean((tp-tt)^2 over Bx3) + mean((2*acos(clip(|dot(qp_hat,qt_hat)|,0,1)))^2 over B)
// Inputs: prediction (B,7) fp32, target (B,7) fp32. Output: 1 fp32 scalar.
// Memory-bound (470 MB read), zero reuse.
// R5 DISCRIMINATOR (recompile: __builtin_nontemporal_load needs a native clang
// ext_vector_type pointer, not HIP's struct float4):
// R2 (LDS sync), R3 (LDS async DMA), R4 (direct) all pinned at ~148 us = 3.2 TB/s
// consumed read BW despite occupancy 18->47%, conflicts ->0, barriers ->none.
// Shared-external-ceiling signature. The one subsystem common to all three:
// allocating reads through L3 (314 MB/dispatch of L3 fills alongside 3.2 TB/s
// delivery). This round: NONTEMPORAL loads (no L3 allocation) force all 470 MB
// through HBM -> directly measures the pure DRAM read ceiling.
//   - L3-fill was the drag, HBM read ~5-6 TB/s: partial -> 80-95 us, FETCH ~470 MB
//   - read path caps ~3.2 TB/s: flat ~147 us, FETCH ~470 MB  -> roofline proven, stop
//   - losing L3 hits hurts: ~165-190 us -> revert, ceiling < 3.2
// Also: 8 rows/thread = 28 independent dwordx4 NT loads per batch, grid 4096 ->
// exactly one pass for B=8.39M.

#define BLOCK 256

typedef float fvec4 __attribute__((ext_vector_type(4)));

__global__ __launch_bounds__(BLOCK) void trl_partial_kernel(
    const float* __restrict__ pred,
    const float* __restrict__ targ,
    float* __restrict__ partial,
    int ngroups8,         // B/8 (number of 8-row groups)
    int tail_start,       // ngroups8*8 (first leftover row)
    int B,
    float inv3B,          // 1/(3B)
    float invB)           // 1/B
{
    const fvec4* __restrict__ p4 = (const fvec4*)pred;
    const fvec4* __restrict__ t4 = (const fvec4*)targ;

    float tsum = 0.0f;  // sum of squared translation diffs
    float rsum = 0.0f;  // sum of angle^2

    const int stride = gridDim.x * BLOCK;
    for (int g = blockIdx.x * BLOCK + threadIdx.x; g < ngroups8; g += stride) {
        const long b = 14L * g;         // 8 rows = 14 float4 per array, contiguous
        fvec4 pa[14], ta[14];
#pragma unroll
        for (int k = 0; k < 14; ++k) pa[k] = __builtin_nontemporal_load(&p4[b + k]);
#pragma unroll
        for (int k = 0; k < 14; ++k) ta[k] = __builtin_nontemporal_load(&t4[b + k]);

        const float* pv = (const float*)pa;
        const float* tv = (const float*)ta;
#pragma unroll
        for (int j = 0; j < 8; ++j) {
            const float* p = pv + 7 * j;
            const float* t = tv + 7 * j;

            float d0 = p[0] - t[0];
            float d1 = p[1] - t[1];
            float d2 = p[2] - t[2];
            tsum += d0 * d0 + d1 * d1 + d2 * d2;

            float np2 = p[3] * p[3] + p[4] * p[4] + p[5] * p[5] + p[6] * p[6];
            float nt2 = t[3] * t[3] + t[4] * t[4] + t[5] * t[5] + t[6] * t[6];
            float dot = p[3] * t[3] + p[4] * t[4] + p[5] * t[5] + p[6] * t[6];
            float c = fabsf(dot) * rsqrtf(np2 * nt2);
            c = fminf(c, 1.0f);
            float ang = 2.0f * acosf(c);
            rsum += ang * ang;
        }
    }

    // --- leftover rows (B % 8 != 0): block 0, scalar path (tiny) ---
    if (blockIdx.x == 0) {
        for (int r = tail_start + threadIdx.x; r < B; r += BLOCK) {
            const long b = 7L * r;
            float p[7], t[7];
#pragma unroll
            for (int k = 0; k < 7; ++k) p[k] = pred[b + k];
#pragma unroll
            for (int k = 0; k < 7; ++k) t[k] = targ[b + k];
            float d0 = p[0] - t[0], d1 = p[1] - t[1], d2 = p[2] - t[2];
            tsum += d0 * d0 + d1 * d1 + d2 * d2;
            float np2 = p[3]*p[3] + p[4]*p[4] + p[5]*p[5] + p[6]*p[6];
            float nt2 = t[3]*t[3] + t[4]*t[4] + t[5]*t[5] + t[6]*t[6];
            float dot = p[3]*t[3] + p[4]*t[4] + p[5]*t[5] + p[6]*t[6];
            float c = fminf(fabsf(dot) * rsqrtf(np2 * nt2), 1.0f);
            float ang = 2.0f * acosf(c);
            rsum += ang * ang;
        }
    }

    float local = tsum * inv3B + rsum * invB;

#pragma unroll
    for (int off = 32; off > 0; off >>= 1)
        local += __shfl_down(local, off, 64);

    __shared__ float sdata[4];
    int lane = threadIdx.x & 63;
    int wave = threadIdx.x >> 6;
    if (lane == 0) sdata[wave] = local;
    __syncthreads();
    if (threadIdx.x == 0)
        partial[blockIdx.x] = sdata[0] + sdata[1] + sdata[2] + sdata[3];
}

__global__ __launch_bounds__(256) void trl_final_kernel(
    const float* __restrict__ partial, int n, float* __restrict__ out)
{
    float s = 0.0f;
    for (int i = threadIdx.x; i < n; i += 256) s += partial[i];
#pragma unroll
    for (int off = 32; off > 0; off >>= 1)
        s += __shfl_down(s, off, 64);
    __shared__ float sd[4];
    if ((threadIdx.x & 63) == 0) sd[threadIdx.x >> 6] = s;
    __syncthreads();
    if (threadIdx.x == 0) out[0] = sd[0] + sd[1] + sd[2] + sd[3];
}

extern "C" void kernel_launch(void* const* d_in, const int* in_sizes, int n_in,
                              void* d_out, int out_size, void* d_ws, size_t ws_size,
                              hipStream_t stream) {
    const float* pred = (const float*)d_in[0];
    const float* targ = (const float*)d_in[1];
    float* out = (float*)d_out;
    float* partial = (float*)d_ws;

    long long total = in_sizes[0];      // B * 7
    int B = (int)(total / 7);           // 8388608
    int ngroups8 = B / 8;               // 1048576
    int tail_start = ngroups8 * 8;      // == B here

    float invB  = 1.0f / (float)B;
    float inv3B = invB / 3.0f;

    // 4096 blocks * 256 threads = 1048576 threads -> exactly one 8-row group per
    // thread for B=8388608 (grid-stride kept for generality).
    const int grid = 4096;

    trl_partial_kernel<<<grid, BLOCK, 0, stream>>>(pred, targ, partial, ngroups8, tail_start, B, inv3B, invB);
    trl_final_kernel<<<1, BLOCK, 0, stream>>>(partial, grid, out);
}